// Round 10
// baseline (11.804 us; speedup 1.0000x reference)
//
#include <hip/hip_runtime.h>
#include <hip/hip_bf16.h>
#include <math.h>

#define NFEAT 10
#define DICT 10000
#define KP32 84            // dword pitch of LDS image rows (336 B, 16B-aligned)

typedef __attribute__((ext_vector_type(8))) short bf16x8;
typedef __attribute__((ext_vector_type(4))) float f32x4;
typedef __attribute__((ext_vector_type(4))) unsigned u32x4;

__device__ inline unsigned short f2bf(float f) {
    __hip_bfloat16 h = __float2bfloat16(f);   // RNE; pairs fuse to v_cvt_pk
    unsigned short s;
    __builtin_memcpy(&s, &h, sizeof(s));
    return s;
}
__device__ inline unsigned cvt2(float lo, float hi) {
    return (unsigned)f2bf(lo) | ((unsigned)f2bf(hi) << 16);   // 2x bf16 packed
}

// block = 256 thr = 4 waves; each wave owns one 16-example tile.
// LDS image (34 rows x 168 bf16): rows 0..31 = K^T (row k holds bf16 K[d][k]),
// row 32 = w, row 33 = -kk2/2.  Per wave: 20 MFMAs total —
//   acc0/acc1 = x @ K (k halves);  accZ = [x | x^2] @ [w ; -kk2/2]
// (accZ's B rows are column-broadcast, so every C column holds lin - t/2).
__global__ __launch_bounds__(256) void fm_fused(
    const int* __restrict__ inputs,
    const float* __restrict__ user_table,
    const float* __restrict__ item_table,
    const float* __restrict__ feat_tables,
    const float* __restrict__ wvec,
    const float* __restrict__ bb,
    const float* __restrict__ k_mat,
    float* __restrict__ out)
{
    __shared__ unsigned ldsK32[34 * KP32];

    const int tid  = threadIdx.x;
    const int lane = tid & 63;
    const int wid  = tid >> 6;
    const int tile = blockIdx.x * 4 + wid;
    const int col  = lane & 15;          // example row (A) / k col (C)
    const int kg   = lane >> 4;          // 8-dim chunk group
    const int e    = tile * 16 + col;
    const int fsel = kg >> 1;            // even/odd feature
    const int hoff = (kg & 1) * 8;       // half of the 16-float embedding

    // ---- 1. issue idx + gather loads FIRST (latency hides under staging) ---
    int idx[5];
    #pragma unroll
    for (int c = 0; c < 5; ++c)
        idx[c] = inputs[e * NFEAT + 2 * c + fsel];

    float4 u0[5], u1[5];
    #pragma unroll
    for (int c = 0; c < 5; ++c) {
        const float* tbl = (c == 0)
            ? (fsel ? item_table : user_table)
            : (feat_tables + (size_t)(2 * c + fsel - 2) * (DICT * 16));
        const float* src = tbl + (size_t)idx[c] * 16 + hoff;
        u0[c] = *(const float4*)src;
        u1[c] = *(const float4*)(src + 4);
    }

    // ---- 2. stage K^T rows 0..31 ----
    #pragma unroll
    for (int u = 0; u < 10; ++u) {
        int i  = tid + 256 * u;          // i = k*80 + d2, 2560 total
        int k  = i / 80;
        int d2 = i - k * 80;
        float flo = k_mat[(2 * d2)     * 32 + k];
        float fhi = k_mat[(2 * d2 + 1) * 32 + k];
        ldsK32[k * KP32 + d2] = cvt2(flo, fhi);
    }
    // ---- row 32: w ; row 33: -kk2/2 (both bf16-packed) ----
    if (tid < 80) {
        ldsK32[32 * KP32 + tid] = cvt2(wvec[2 * tid], wvec[2 * tid + 1]);
    } else if (tid < 160) {
        int d2 = tid - 80;
        const float4* r0 = (const float4*)(k_mat + (2 * d2)     * 32);
        const float4* r1 = (const float4*)(k_mat + (2 * d2 + 1) * 32);
        float a0 = 0.f, a1 = 0.f;
        #pragma unroll
        for (int u = 0; u < 8; ++u) {
            float4 v = r0[u], w = r1[u];
            a0 = fmaf(v.x, v.x, a0); a0 = fmaf(v.y, v.y, a0);
            a0 = fmaf(v.z, v.z, a0); a0 = fmaf(v.w, v.w, a0);
            a1 = fmaf(w.x, w.x, a1); a1 = fmaf(w.y, w.y, a1);
            a1 = fmaf(w.z, w.z, a1); a1 = fmaf(w.w, w.w, a1);
        }
        ldsK32[33 * KP32 + d2] = cvt2(-0.5f * a0, -0.5f * a1);
    }
    __syncthreads();

    const unsigned short* ldsK16 = (const unsigned short*)ldsK32;

    // ---- 3. main loop: per chunk load 4 B-frags, pack a/a^2, 4 MFMAs ----
    f32x4 acc0 = {0,0,0,0};   // s, k = 0..15
    f32x4 acc1 = {0,0,0,0};   // s, k = 16..31
    f32x4 accZ = {0,0,0,0};   // lin - t/2 (all columns identical)
    #pragma unroll
    for (int c = 0; c < 5; ++c) {
        const int dbase = c * 32 + kg * 8;
        bf16x8 b0 = *(const bf16x8*)&ldsK16[(col)      * (2 * KP32) + dbase];
        bf16x8 b1 = *(const bf16x8*)&ldsK16[(col + 16) * (2 * KP32) + dbase];
        bf16x8 bw = *(const bf16x8*)&ldsK16[32         * (2 * KP32) + dbase];
        bf16x8 bq = *(const bf16x8*)&ldsK16[33         * (2 * KP32) + dbase];

        u32x4 p, q;
        p[0] = cvt2(u0[c].x, u0[c].y); p[1] = cvt2(u0[c].z, u0[c].w);
        p[2] = cvt2(u1[c].x, u1[c].y); p[3] = cvt2(u1[c].z, u1[c].w);
        q[0] = cvt2(u0[c].x*u0[c].x, u0[c].y*u0[c].y);
        q[1] = cvt2(u0[c].z*u0[c].z, u0[c].w*u0[c].w);
        q[2] = cvt2(u1[c].x*u1[c].x, u1[c].y*u1[c].y);
        q[3] = cvt2(u1[c].z*u1[c].z, u1[c].w*u1[c].w);
        bf16x8 a  = __builtin_bit_cast(bf16x8, p);
        bf16x8 a2 = __builtin_bit_cast(bf16x8, q);

        acc0 = __builtin_amdgcn_mfma_f32_16x16x32_bf16(a,  b0, acc0, 0, 0, 0);
        acc1 = __builtin_amdgcn_mfma_f32_16x16x32_bf16(a,  b1, acc1, 0, 0, 0);
        accZ = __builtin_amdgcn_mfma_f32_16x16x32_bf16(a,  bw, accZ, 0, 0, 0);
        accZ = __builtin_amdgcn_mfma_f32_16x16x32_bf16(a2, bq, accZ, 0, 0, 0);
    }

    // ---- 4. epilogue: C row = kg*4+r (example), col = k ----
    const float bval = bb[0];
    #pragma unroll
    for (int r = 0; r < 4; ++r) {
        float v = acc0[r]*acc0[r] + acc1[r]*acc1[r];   // s_k^2 pair
        #pragma unroll
        for (int m = 1; m <= 8; m <<= 1)
            v += __shfl_xor(v, m, 64);                 // sum over 16 k-cols
        if (col == 0) {
            float z = accZ[r] + bval + 0.5f * v;       // lin - t/2 + b + s²/2
            out[tile * 16 + kg * 4 + r] = 1.0f / (1.0f + __expf(-z));
        }
    }
}

extern "C" void kernel_launch(void* const* d_in, const int* in_sizes, int n_in,
                              void* d_out, int out_size, void* d_ws, size_t ws_size,
                              hipStream_t stream) {
    const int*   inputs      = (const int*)  d_in[0];
    const float* user_table  = (const float*)d_in[1];
    const float* item_table  = (const float*)d_in[2];
    const float* feat_tables = (const float*)d_in[3];
    const float* w           = (const float*)d_in[4];
    const float* b           = (const float*)d_in[5];
    const float* k_mat       = (const float*)d_in[6];
    float* out = (float*)d_out;

    int nblocks = out_size / 64;    // 16384 / (4 waves * 16 examples) = 256
    fm_fused<<<nblocks, 256, 0, stream>>>(inputs, user_table, item_table,
                                          feat_tables, w, b, k_mat, out);
}